// Round 5
// baseline (302.700 us; speedup 1.0000x reference)
//
#include <hip/hip_runtime.h>
#include <hip/hip_bf16.h>
#include <stdint.h>

// Problem constants (head_2327872274482): B=1024, T=256, C=195, H=8
#define TT    256
#define CC    195
#define HH    8
#define NKT   7     // projection K-tiles of 32 (7*32 = 224 >= 195)
#define VSTR  260   // Vt row stride (shorts)

typedef __attribute__((ext_vector_type(8))) short short8;   // bf16 MFMA A/B frag
typedef __attribute__((ext_vector_type(4))) short short4v;  // half-frag (8 B)
typedef __attribute__((ext_vector_type(4))) float f32x4;    // MFMA C/D frag

typedef __attribute__((address_space(1))) const unsigned int g_u32;  // global
typedef __attribute__((address_space(3))) unsigned int l_u32;        // LDS

static __device__ __forceinline__ short f2bf(float v) {
    union { __hip_bfloat16 h; short s; } cv;
    cv.h = __float2bfloat16(v);
    return cv.s;
}

// LDS: Xs 49920 + Ql 4096 + Kl 4096 + Vt 8320 = 66.4 KB -> 2 blocks/CU.
//
// x is staged raw (fp32) into LDS via global_load_lds width-16: perfectly
// coalesced 1 KB/instr vs the old 56 scattered dwords (256 B/instr over ~32
// cache lines). Xs is WAVE-PRIVATE: wave wv stages exactly rows wv*16..+15
// (780 units), so the DMA needs only per-wave vmcnt(0) -- no barriers -- and
// issue(s+1) stays in flight across the stage barrier while attn computes
// (T14/T4: counted drain after the covering compute phase).
__global__ __launch_bounds__(256, 2)
void fused_head(const float* __restrict__ x,
                const float* __restrict__ Wq,
                const float* __restrict__ Wk,
                const float* __restrict__ Wv,
                float* __restrict__ out)
{
    __shared__ __align__(16) float Xs[64 * CC];      // raw fp32 chunk (49,920 B)
    __shared__ __align__(16) short Ql[TT * 8];       // Q rows, 8 bf16 features
    __shared__ __align__(16) short Kl[TT * 8];       // K rows, same
    __shared__ __align__(16) short Vt[16 * VSTR];    // V^T: n<8 = v_h; n=8 = 1.0; n>8 = 0

    const int tid  = threadIdx.x;
    const int lane = tid & 63;
    const int wv   = __builtin_amdgcn_readfirstlane(tid >> 6);
    const int b    = blockIdx.x;
    const int nn   = lane & 15;
    const int quad = lane >> 4;

    const float* __restrict__ xb = x + (size_t)b * (TT * CC);

    // ---- issue(ch): DMA chunk ch's x rows for THIS wave into Xs (wave-private).
    // 780 16-B units/wave = rows wv*16..wv*16+15 exactly. 12 full calls + 12-lane tail.
    auto issue = [&](int ch) {
        const char* src = (const char*)(xb + (size_t)ch * 64 * CC);
        char* dst = (char*)Xs;
        const int ubase = wv * 780;              // this wave's first 16-B unit
#pragma unroll
        for (int j = 0; j < 13; ++j) {
            const int u = ubase + j * 64 + lane;
            if (j < 12 || lane < 12)
                __builtin_amdgcn_global_load_lds(
                    (g_u32*)(src + (size_t)u * 16),
                    (l_u32*)(dst + (size_t)(ubase + j * 64) * 16),
                    16, 0, 0);
        }
    };

    // ---- projection B-frag preload (verified layout: B[k=quad*8+j][n=lane&15])
    const float* Wsel0 = (nn < 8) ? (Wq + nn) : (Wk + nn - 8);
    const float* Wsel1 = (nn < 8) ? (Wv + nn) : nullptr;
    short8 Bf[NKT][2];

    // ---- consume(ch): frags from Xs (ds_read_b32; 195-word stride -> 2-way banks,
    // free), cvt, MFMA, store q/k/v into attention-ready LDS rows ch*64..ch*64+63.
    auto consume = [&](int ch) {
        const int rbase = ch * 64 + wv * 16;
        const float* xr = Xs + (wv * 16 + nn) * CC;   // this lane's row (wave-private)

        f32x4 acc0 = {0.f, 0.f, 0.f, 0.f};
        f32x4 acc1 = {0.f, 0.f, 0.f, 0.f};
#pragma unroll
        for (int kt = 0; kt < 6; ++kt) {              // k = 0..191, no masking needed
            short8 a;
#pragma unroll
            for (int j = 0; j < 8; ++j)
                a[j] = f2bf(xr[kt * 32 + quad * 8 + j]);
            acc0 = __builtin_amdgcn_mfma_f32_16x16x32_bf16(a, Bf[kt][0], acc0, 0, 0, 0);
            acc1 = __builtin_amdgcn_mfma_f32_16x16x32_bf16(a, Bf[kt][1], acc1, 0, 0, 0);
        }
        {   // kt = 6: only quad 0, words 192..194 valid (k<195); rest zero
            float g0 = 0.f, g1 = 0.f, g2 = 0.f;
            if (quad == 0) { g0 = xr[192]; g1 = xr[193]; g2 = xr[194]; }
            short8 a = (short8){f2bf(g0), f2bf(g1), f2bf(g2), 0, 0, 0, 0, 0};
            acc0 = __builtin_amdgcn_mfma_f32_16x16x32_bf16(a, Bf[6][0], acc0, 0, 0, 0);
            acc1 = __builtin_amdgcn_mfma_f32_16x16x32_bf16(a, Bf[6][1], acc1, 0, 0, 0);
        }
        // C/D layout: col = lane&15, row = quad*4 + reg
#pragma unroll
        for (int r = 0; r < 4; ++r) {
            const int trow = rbase + quad * 4 + r;
            const short qs = f2bf(acc0[r]);
            if (nn < 8) {
                Ql[trow * 8 + nn] = qs;                  // Q[row][feature]
                Vt[nn * VSTR + trow] = f2bf(acc1[r]);    // Vt[feature][key]
            } else {
                Kl[trow * 8 + (nn - 8)] = qs;            // K[row][feature]
            }
        }
    };

    const float SC2 = 0.07161149f * 1.44269504f;   // (1/sqrt(195)) * log2(e)

    // ---- one q-tile of MFMA attention, register-resident P (swapped QK^T)
    auto attn_tile = [&](int qt) {
        const int qb = qt * 16;
        const int qcol = qb + nn;                 // this lane's q (S^T column)

        short8 bQ = (short8){0, 0, 0, 0, 0, 0, 0, 0};
        if (quad == 0)
            bQ = *reinterpret_cast<const short8*>(Ql + (qb + nn) * 8);

        f32x4 accO = {0.f, 0.f, 0.f, 0.f};       // cols: 0..7 = o_h, 8 = denom
        const int nch = (qt >> 1) + 1;            // 32-key chunks covering keys<=qb+15
        for (int c = 0; c < nch; ++c) {
            const int kb = c * 32;
            const bool doH1 = (c < nch - 1) || (qt & 1);   // diagonal-half skip

            short8 aK0 = (short8){0, 0, 0, 0, 0, 0, 0, 0};
            short8 aK1 = (short8){0, 0, 0, 0, 0, 0, 0, 0};
            if (quad == 0) {
                aK0 = *reinterpret_cast<const short8*>(Kl + (kb + nn) * 8);
                if (doH1)
                    aK1 = *reinterpret_cast<const short8*>(Kl + (kb + 16 + nn) * 8);
            }
            f32x4 s0 = __builtin_amdgcn_mfma_f32_16x16x32_bf16(
                           aK0, bQ, (f32x4){0.f, 0.f, 0.f, 0.f}, 0, 0, 0);
            f32x4 s1 = {0.f, 0.f, 0.f, 0.f};
            if (doH1)
                s1 = __builtin_amdgcn_mfma_f32_16x16x32_bf16(
                         aK1, bQ, (f32x4){0.f, 0.f, 0.f, 0.f}, 0, 0, 0);

            const short* vrow = Vt + nn * VSTR + kb + quad * 4;
            const short4v v0 = *reinterpret_cast<const short4v*>(vrow);
            const short4v v1 = *reinterpret_cast<const short4v*>(vrow + 16);

            const int keyb = kb + quad * 4;
            short8 aP, bV;
#pragma unroll
            for (int r = 0; r < 4; ++r) {
                const float e0 = (keyb + r <= qcol) ? exp2f(s0[r] * SC2) : 0.f;
                const float e1 = (doH1 && (keyb + 16 + r <= qcol))
                                     ? exp2f(s1[r] * SC2) : 0.f;
                aP[r]     = f2bf(e0);
                aP[4 + r] = f2bf(e1);
                bV[r]     = v0[r];
                bV[4 + r] = v1[r];
            }
            accO = __builtin_amdgcn_mfma_f32_16x16x32_bf16(aP, bV, accO, 0, 0, 0);
        }

#pragma unroll
        for (int r = 0; r < 4; ++r) {
            const float dn = __shfl(accO[r], (lane & 48) | 8);
            if (nn < 8) {
                const int q = qb + quad * 4 + r;
                out[((size_t)b * TT + q) * HH + nn] = accO[r] / dn;
            }
        }
    };

    // ================= schedule =================
    issue(0);                          // chunk-0 DMA in flight immediately
    __builtin_amdgcn_sched_barrier(0);

    // Vt rows 8..15: row 8 = ones (denom column), rows 9..15 = 0
    {
        uint32_t* vtw = (uint32_t*)Vt;
        const int base = (8 * VSTR) / 2;
        for (int i = tid; i < (8 * VSTR) / 2; i += 256)
            vtw[base + i] = (i < VSTR / 2) ? 0x3F803F80u : 0u;
    }
    // Bf preload (W matrices are tiny + L2/L3-hot across the 1024 blocks)
#pragma unroll
    for (int kt = 0; kt < NKT; ++kt) {
#pragma unroll
        for (int j = 0; j < 8; ++j) {
            const int k = kt * 32 + quad * 8 + j;
            float v0 = (k < CC) ? Wsel0[(size_t)k * HH] : 0.f;
            float v1 = (k < CC && Wsel1) ? Wsel1[(size_t)k * HH] : 0.f;
            Bf[kt][0][j] = f2bf(v0);
            Bf[kt][1][j] = f2bf(v1);
        }
    }

    asm volatile("s_waitcnt vmcnt(0)" ::: "memory");   // Xs(0) + Bf landed
    __builtin_amdgcn_sched_barrier(0);
    consume(0);                        // rows 0..63 -> Ql/Kl/Vt
    __builtin_amdgcn_sched_barrier(0);
    issue(1);                          // in flight across the barrier + attn
    asm volatile("s_waitcnt lgkmcnt(0)" ::: "memory");
    __builtin_amdgcn_s_barrier();      // rows 0..63 (+Vt init) visible to all waves
    __builtin_amdgcn_sched_barrier(0);

    attn_tile(wv);                     // tiles 0..3   (chunks 1,1,2,2)
    asm volatile("s_waitcnt vmcnt(0)" ::: "memory");   // Xs(1) landed (wave-private)
    __builtin_amdgcn_sched_barrier(0);
    consume(1);                        // rows 64..127
    __builtin_amdgcn_sched_barrier(0);
    issue(2);
    asm volatile("s_waitcnt lgkmcnt(0)" ::: "memory");
    __builtin_amdgcn_s_barrier();      // rows 0..127 visible
    __builtin_amdgcn_sched_barrier(0);

    attn_tile(4 + (wv ^ 1));           // tiles 4..7   (chunks 3,3,4,4)
    asm volatile("s_waitcnt vmcnt(0)" ::: "memory");
    __builtin_amdgcn_sched_barrier(0);
    consume(2);                        // rows 128..191
    __builtin_amdgcn_sched_barrier(0);
    issue(3);
    asm volatile("s_waitcnt lgkmcnt(0)" ::: "memory");
    __builtin_amdgcn_s_barrier();      // rows 0..191 visible
    __builtin_amdgcn_sched_barrier(0);

    attn_tile(8 + (wv ^ 2));           // tiles 8..11  (chunks 6,6,5,5)
    asm volatile("s_waitcnt vmcnt(0)" ::: "memory");
    __builtin_amdgcn_sched_barrier(0);
    consume(3);                        // rows 192..255
    asm volatile("s_waitcnt lgkmcnt(0)" ::: "memory");
    __builtin_amdgcn_s_barrier();      // all rows visible
    __builtin_amdgcn_sched_barrier(0);

    attn_tile(12 + (wv ^ 3));          // tiles 12..15 (chunks 8,8,7,7)
}

extern "C" void kernel_launch(void* const* d_in, const int* in_sizes, int n_in,
                              void* d_out, int out_size, void* d_ws, size_t ws_size,
                              hipStream_t stream)
{
    const float* x  = (const float*)d_in[0];
    const float* Wq = (const float*)d_in[1];
    const float* Wk = (const float*)d_in[2];
    const float* Wv = (const float*)d_in[3];
    float* out      = (float*)d_out;
    const int B = in_sizes[0] / (TT * CC);   // = 1024
    fused_head<<<dim3(B), dim3(256), 0, stream>>>(x, Wq, Wk, Wv, out);
}

// Round 6
// 298.652 us; speedup vs baseline: 1.0136x; 1.0136x over previous
//
#include <hip/hip_runtime.h>
#include <hip/hip_bf16.h>
#include <stdint.h>

// Problem constants (head_2327872274482): B=1024, T=256, C=195, H=8
#define TT    256
#define CC    195
#define HH    8
#define NKT   7     // projection K-tiles of 32 (7*32 = 224 >= 195)
#define VSTR  260   // Vt row stride (shorts)
#define WSETS 14    // W fragment sets: 7 kt x {QK, V}
#define WLSTR 40    // Wl row stride in shorts (80 B -> 2-way banks, free)

typedef __attribute__((ext_vector_type(8))) short short8;   // bf16 MFMA A/B frag
typedef __attribute__((ext_vector_type(4))) short short4v;  // half-frag (8 B)
typedef __attribute__((ext_vector_type(4))) float f32x4;    // MFMA C/D frag

static __device__ __forceinline__ short f2bf(float v) {
    union { __hip_bfloat16 h; short s; } cv;
    cv.h = __float2bfloat16(v);
    return cv.s;
}

// LDS: Ql 4096 + Kl 4096 + Vt 8320 + Wl 17920 = 34.4 KB; VGPR<=128 -> 4 blocks/CU.
//
// R4 skeleton (reg-prefetch T14, Wl in LDS, lgkm-only barriers) with the x
// prefetch SPLIT A/B: consume starts MFMAs when the A-half (kt 0-3) lands,
// and issueA(s+1) is injected mid-consume (xpA dead by then, WAR-safe) so
// memory demand stays continuous instead of burst-then-silence per stage.
__global__ __launch_bounds__(256, 4)
void fused_head(const float* __restrict__ x,
                const float* __restrict__ Wq,
                const float* __restrict__ Wk,
                const float* __restrict__ Wv,
                float* __restrict__ out)
{
    __shared__ __align__(16) short Ql[TT * 8];       // Q rows, 8 bf16 features
    __shared__ __align__(16) short Kl[TT * 8];       // K rows, same
    __shared__ __align__(16) short Vt[16 * VSTR];    // V^T: n<8 = v_h; n=8 = 1.0; n>8 = 0
    __shared__ __align__(16) short Wl[WSETS * 16 * WLSTR];  // proj B-frags

    const int tid  = threadIdx.x;
    const int lane = tid & 63;
    const int wv   = __builtin_amdgcn_readfirstlane(tid >> 6);
    const int b    = blockIdx.x;
    const int nn   = lane & 15;
    const int quad = lane >> 4;

    const float* __restrict__ xb = x + (size_t)b * (TT * CC);

    float xpA[4][8];   // kt 0..3 (k 0..127)   -- 32 VGPR
    float xpB[3][8];   // kt 4..6 (k 128..194) -- 24 VGPR

    // ---- issueA/B(ch): put chunk ch's x loads in flight (no consumption)
    auto issueA = [&](int ch) {
        const float* __restrict__ xrow = xb + (size_t)(ch * 64 + wv * 16 + nn) * CC;
#pragma unroll
        for (int kt = 0; kt < 4; ++kt)
#pragma unroll
            for (int j = 0; j < 8; ++j)
                xpA[kt][j] = xrow[kt * 32 + quad * 8 + j];      // k<=127, no mask
    };
    auto issueB = [&](int ch) {
        const float* __restrict__ xrow = xb + (size_t)(ch * 64 + wv * 16 + nn) * CC;
#pragma unroll
        for (int kt = 4; kt < 7; ++kt)
#pragma unroll
            for (int j = 0; j < 8; ++j) {
                const int k = kt * 32 + quad * 8 + j;
                xpB[kt - 4][j] = (k < CC) ? xrow[k] : 0.f;      // only kt=6 masks
            }
    };

    // ---- consume(ch): A-half MFMAs -> issueA(nxt) -> B-half MFMAs ->
    // C-write -> issueB(nxt). B-frags come from Wl (2-way banks, free).
    auto consume = [&](int ch, int nxt) {
        const int rbase = ch * 64 + wv * 16;
        f32x4 acc0 = {0.f, 0.f, 0.f, 0.f};
        f32x4 acc1 = {0.f, 0.f, 0.f, 0.f};
#pragma unroll
        for (int kt = 0; kt < 4; ++kt) {
            short8 a;
#pragma unroll
            for (int j = 0; j < 8; ++j) a[j] = f2bf(xpA[kt][j]);
            const short8 b0 = *reinterpret_cast<const short8*>(
                Wl + ((kt * 2 + 0) * 16 + nn) * WLSTR + quad * 8);
            const short8 b1 = *reinterpret_cast<const short8*>(
                Wl + ((kt * 2 + 1) * 16 + nn) * WLSTR + quad * 8);
            acc0 = __builtin_amdgcn_mfma_f32_16x16x32_bf16(a, b0, acc0, 0, 0, 0);
            acc1 = __builtin_amdgcn_mfma_f32_16x16x32_bf16(a, b1, acc1, 0, 0, 0);
        }
        if (nxt >= 0) issueA(nxt);            // xpA dead; refill in flight
        __builtin_amdgcn_sched_barrier(0);    // pin the issue before B-half
#pragma unroll
        for (int kt = 4; kt < 7; ++kt) {
            short8 a;
#pragma unroll
            for (int j = 0; j < 8; ++j) a[j] = f2bf(xpB[kt - 4][j]);
            const short8 b0 = *reinterpret_cast<const short8*>(
                Wl + ((kt * 2 + 0) * 16 + nn) * WLSTR + quad * 8);
            const short8 b1 = *reinterpret_cast<const short8*>(
                Wl + ((kt * 2 + 1) * 16 + nn) * WLSTR + quad * 8);
            acc0 = __builtin_amdgcn_mfma_f32_16x16x32_bf16(a, b0, acc0, 0, 0, 0);
            acc1 = __builtin_amdgcn_mfma_f32_16x16x32_bf16(a, b1, acc1, 0, 0, 0);
        }
        // C/D layout: col = lane&15, row = quad*4 + reg
#pragma unroll
        for (int r = 0; r < 4; ++r) {
            const int trow = rbase + quad * 4 + r;
            const short qs = f2bf(acc0[r]);
            if (nn < 8) {
                Ql[trow * 8 + nn] = qs;                  // Q[row][feature]
                Vt[nn * VSTR + trow] = f2bf(acc1[r]);    // Vt[feature][key]
            } else {
                Kl[trow * 8 + (nn - 8)] = qs;            // K[row][feature]
            }
        }
        if (nxt >= 0) issueB(nxt);
    };

    const float SC2 = 0.07161149f * 1.44269504f;   // (1/sqrt(195)) * log2(e)

    // ---- one q-tile of MFMA attention, register-resident P (swapped QK^T)
    auto attn_tile = [&](int qt) {
        const int qb = qt * 16;
        const int qcol = qb + nn;                 // this lane's q (S^T column)

        short8 bQ = (short8){0, 0, 0, 0, 0, 0, 0, 0};
        if (quad == 0)
            bQ = *reinterpret_cast<const short8*>(Ql + (qb + nn) * 8);

        f32x4 accO = {0.f, 0.f, 0.f, 0.f};       // cols: 0..7 = o_h, 8 = denom
        const int nch = (qt >> 1) + 1;            // 32-key chunks covering keys<=qb+15
        for (int c = 0; c < nch; ++c) {
            const int kb = c * 32;
            const bool doH1 = (c < nch - 1) || (qt & 1);   // diagonal-half skip

            short8 aK0 = (short8){0, 0, 0, 0, 0, 0, 0, 0};
            short8 aK1 = (short8){0, 0, 0, 0, 0, 0, 0, 0};
            if (quad == 0) {
                aK0 = *reinterpret_cast<const short8*>(Kl + (kb + nn) * 8);
                if (doH1)
                    aK1 = *reinterpret_cast<const short8*>(Kl + (kb + 16 + nn) * 8);
            }
            f32x4 s0 = __builtin_amdgcn_mfma_f32_16x16x32_bf16(
                           aK0, bQ, (f32x4){0.f, 0.f, 0.f, 0.f}, 0, 0, 0);
            f32x4 s1 = {0.f, 0.f, 0.f, 0.f};
            if (doH1)
                s1 = __builtin_amdgcn_mfma_f32_16x16x32_bf16(
                         aK1, bQ, (f32x4){0.f, 0.f, 0.f, 0.f}, 0, 0, 0);

            const short* vrow = Vt + nn * VSTR + kb + quad * 4;
            const short4v v0 = *reinterpret_cast<const short4v*>(vrow);
            const short4v v1 = *reinterpret_cast<const short4v*>(vrow + 16);

            const int keyb = kb + quad * 4;
            short8 aP, bV;
#pragma unroll
            for (int r = 0; r < 4; ++r) {
                const float e0 = (keyb + r <= qcol) ? exp2f(s0[r] * SC2) : 0.f;
                const float e1 = (doH1 && (keyb + 16 + r <= qcol))
                                     ? exp2f(s1[r] * SC2) : 0.f;
                aP[r]     = f2bf(e0);
                aP[4 + r] = f2bf(e1);
                bV[r]     = v0[r];
                bV[4 + r] = v1[r];
            }
            accO = __builtin_amdgcn_mfma_f32_16x16x32_bf16(aP, bV, accO, 0, 0, 0);
        }

#pragma unroll
        for (int r = 0; r < 4; ++r) {
            const float dn = __shfl(accO[r], (lane & 48) | 8);
            if (nn < 8) {
                const int q = qb + quad * 4 + r;
                out[((size_t)b * TT + q) * HH + nn] = accO[r] / dn;
            }
        }
    };

    // LDS-visibility barrier that does NOT drain vmcnt (prefetch rides through)
    auto barrier_lds = [&]() {
        asm volatile("s_waitcnt lgkmcnt(0)" ::: "memory");
        __builtin_amdgcn_s_barrier();
        __builtin_amdgcn_sched_barrier(0);
    };

    // ================= prologue =================
    // Pass 1: issue W loads FIRST (retire before xp), then x chunk-0 loads.
    const float* Wsel0 = (nn < 8) ? (Wq + nn) : (Wk + nn - 8);
    const float* Wsel1 = Wv + (nn & 7);          // safe ptr; masked by nn<8
    float wt[4][8];                               // this wave's sets: wv+4i
#pragma unroll
    for (int i = 0; i < 4; ++i) {
        const int set = wv + i * 4;
        const int kt = set >> 1, sv = set & 1;
#pragma unroll
        for (int j = 0; j < 8; ++j) {
            const int k = kt * 32 + quad * 8 + j;
            float v = 0.f;
            if (set < WSETS && k < CC)
                v = (sv == 0) ? Wsel0[(size_t)k * HH]
                              : ((nn < 8) ? Wsel1[(size_t)k * HH] : 0.f);
            wt[i][j] = v;
        }
    }
    __builtin_amdgcn_sched_barrier(0);
    issueA(0);
    issueB(0);
    __builtin_amdgcn_sched_barrier(0);

    // Vt rows 8..15: row 8 = ones (denom column), rows 9..15 = 0
    {
        uint32_t* vtw = (uint32_t*)Vt;
        const int base = (8 * VSTR) / 2;
        for (int i = tid; i < (8 * VSTR) / 2; i += 256)
            vtw[base + i] = (i < VSTR / 2) ? 0x3F803F80u : 0u;
    }
    // Pass 2: cvt + store W frags (waits only W loads, vmcnt(56) -- xp rides)
#pragma unroll
    for (int i = 0; i < 4; ++i) {
        const int set = wv + i * 4;
        if (set < WSETS) {
            short8 frag;
#pragma unroll
            for (int j = 0; j < 8; ++j) frag[j] = f2bf(wt[i][j]);
            *reinterpret_cast<short8*>(Wl + (set * 16 + nn) * WLSTR + quad * 8) = frag;
        }
    }
    barrier_lds();                 // Wl + Vt init visible

    // ================= pipelined stages =================
    consume(0, 1);                 // rows 0..63; chunk-1 loads injected mid-consume
    barrier_lds();                 // rows 0..63 visible

    attn_tile(wv);                 // tiles 0..3   (chunks 1,1,2,2)
    consume(1, 2);                 // rows 64..127; chunk-2 in flight
    barrier_lds();                 // rows 0..127 visible

    attn_tile(4 + (wv ^ 1));       // tiles 4..7   (chunks 3,3,4,4)
    consume(2, 3);                 // rows 128..191; chunk-3 in flight
    barrier_lds();                 // rows 0..191 visible

    attn_tile(8 + (wv ^ 2));       // tiles 8..11  (chunks 6,6,5,5)
    consume(3, -1);                // rows 192..255
    barrier_lds();                 // all rows visible

    attn_tile(12 + (wv ^ 3));      // tiles 12..15 (chunks 8,8,7,7)
}

extern "C" void kernel_launch(void* const* d_in, const int* in_sizes, int n_in,
                              void* d_out, int out_size, void* d_ws, size_t ws_size,
                              hipStream_t stream)
{
    const float* x  = (const float*)d_in[0];
    const float* Wq = (const float*)d_in[1];
    const float* Wk = (const float*)d_in[2];
    const float* Wv = (const float*)d_in[3];
    float* out      = (float*)d_out;
    const int B = in_sizes[0] / (TT * CC);   // = 1024
    fused_head<<<dim3(B), dim3(256), 0, stream>>>(x, Wq, Wk, Wv, out);
}

// Round 7
// 298.526 us; speedup vs baseline: 1.0140x; 1.0004x over previous
//
#include <hip/hip_runtime.h>
#include <hip/hip_bf16.h>
#include <stdint.h>

// Problem constants (head_2327872274482): B=1024, T=256, C=195, H=8
#define TT    256
#define CC    195
#define HH    8
#define NKT   7     // projection K-tiles of 32 (7*32 = 224 >= 195)
#define VSTR  260   // Vt row stride (shorts)
#define WSETS 14    // W fragment sets: 7 kt x {QK, V}
#define WLSTR 40    // Wl row stride in shorts (80 B = 4 quads x 16 B + 16 B pad -> 2-way banks)

typedef __attribute__((ext_vector_type(8))) short short8;   // bf16 MFMA A/B frag
typedef __attribute__((ext_vector_type(4))) short short4v;  // half-frag (8 B)
typedef __attribute__((ext_vector_type(4))) float f32x4;    // MFMA C/D frag

static __device__ __forceinline__ short f2bf(float v) {
    union { __hip_bfloat16 h; short s; } cv;
    cv.h = __float2bfloat16(v);
    return cv.s;
}

// LDS: Ql 4096 + Kl 4096 + Vt 8320 + Wl 17920 = 34.4 KB; VGPR<=128 -> 4 blocks/CU.
//
// ASYNC-STAGE SPLIT (T14): x loads for chunk ch+1 are ISSUED (to registers)
// before attn stage s and CONSUMED after it -> HBM latency hides under the
// attn compute phase. W-fragments live in LDS (Wl) to free the 56 VGPRs the
// prefetch needs. Barriers are raw s_barrier + write-side lgkmcnt(0) only —
// __syncthreads would vmcnt(0)-drain the prefetch (m97 barrier-drain).
// [R4 = best verified variant, 296.4 us. R5 (DMA staging) and R6 (split
//  prefetch) both regressed; reverted to this exact structure.]
__global__ __launch_bounds__(256, 4)
void fused_head(const float* __restrict__ x,
                const float* __restrict__ Wq,
                const float* __restrict__ Wk,
                const float* __restrict__ Wv,
                float* __restrict__ out)
{
    __shared__ __align__(16) short Ql[TT * 8];       // Q rows, 8 bf16 features
    __shared__ __align__(16) short Kl[TT * 8];       // K rows, same
    __shared__ __align__(16) short Vt[16 * VSTR];    // V^T: row n<8 = v_h; n=8 = 1.0; n>8 = 0
    __shared__ __align__(16) short Wl[WSETS * 16 * WLSTR];  // proj B-frags

    const int tid  = threadIdx.x;
    const int lane = tid & 63;
    const int wv   = __builtin_amdgcn_readfirstlane(tid >> 6);
    const int b    = blockIdx.x;
    const int nn   = lane & 15;
    const int quad = lane >> 4;

    const float* __restrict__ xb = x + (size_t)b * (TT * CC);

    float xp[NKT][8];   // prefetched x slice (56 VGPR), all indices static

    // ---- issue(ch): put chunk ch's x loads in flight (no consumption here)
    auto issue = [&](int ch) {
        const float* __restrict__ xrow = xb + (size_t)(ch * 64 + wv * 16 + nn) * CC;
#pragma unroll
        for (int kt = 0; kt < NKT; ++kt)
#pragma unroll
            for (int j = 0; j < 8; ++j) {
                const int k = kt * 32 + quad * 8 + j;
                xp[kt][j] = (k < CC) ? xrow[k] : 0.f;
            }
    };

    // ---- consume(ch): cvt + MFMA (B-frags from Wl) + store q/k/v to LDS
    auto consume = [&](int ch) {
        const int rbase = ch * 64 + wv * 16;
        f32x4 acc0 = {0.f, 0.f, 0.f, 0.f};
        f32x4 acc1 = {0.f, 0.f, 0.f, 0.f};
#pragma unroll
        for (int kt = 0; kt < NKT; ++kt) {
            short8 a;
#pragma unroll
            for (int j = 0; j < 8; ++j) a[j] = f2bf(xp[kt][j]);
            const short8 b0 = *reinterpret_cast<const short8*>(
                Wl + ((kt * 2 + 0) * 16 + nn) * WLSTR + quad * 8);
            const short8 b1 = *reinterpret_cast<const short8*>(
                Wl + ((kt * 2 + 1) * 16 + nn) * WLSTR + quad * 8);
            acc0 = __builtin_amdgcn_mfma_f32_16x16x32_bf16(a, b0, acc0, 0, 0, 0);
            acc1 = __builtin_amdgcn_mfma_f32_16x16x32_bf16(a, b1, acc1, 0, 0, 0);
        }
        // C/D layout: col = lane&15, row = quad*4 + reg
#pragma unroll
        for (int r = 0; r < 4; ++r) {
            const int trow = rbase + quad * 4 + r;
            const short qs = f2bf(acc0[r]);
            if (nn < 8) {
                Ql[trow * 8 + nn] = qs;                  // Q[row][feature]
                Vt[nn * VSTR + trow] = f2bf(acc1[r]);    // Vt[feature][key]
            } else {
                Kl[trow * 8 + (nn - 8)] = qs;            // K[row][feature]
            }
        }
    };

    const float SC2 = 0.07161149f * 1.44269504f;   // (1/sqrt(195)) * log2(e)

    // ---- one q-tile of MFMA attention, register-resident P (swapped QK^T)
    auto attn_tile = [&](int qt) {
        const int qb = qt * 16;
        const int qcol = qb + nn;                 // this lane's q (S^T column)

        short8 bQ = (short8){0, 0, 0, 0, 0, 0, 0, 0};
        if (quad == 0)
            bQ = *reinterpret_cast<const short8*>(Ql + (qb + nn) * 8);

        f32x4 accO = {0.f, 0.f, 0.f, 0.f};       // cols: 0..7 = o_h, 8 = denom
        const int nch = (qt >> 1) + 1;            // 32-key chunks covering keys<=qb+15
        for (int c = 0; c < nch; ++c) {
            const int kb = c * 32;
            const bool doH1 = (c < nch - 1) || (qt & 1);   // diagonal-half skip

            short8 aK0 = (short8){0, 0, 0, 0, 0, 0, 0, 0};
            short8 aK1 = (short8){0, 0, 0, 0, 0, 0, 0, 0};
            if (quad == 0) {
                aK0 = *reinterpret_cast<const short8*>(Kl + (kb + nn) * 8);
                if (doH1)
                    aK1 = *reinterpret_cast<const short8*>(Kl + (kb + 16 + nn) * 8);
            }
            f32x4 s0 = __builtin_amdgcn_mfma_f32_16x16x32_bf16(
                           aK0, bQ, (f32x4){0.f, 0.f, 0.f, 0.f}, 0, 0, 0);
            f32x4 s1 = {0.f, 0.f, 0.f, 0.f};
            if (doH1)
                s1 = __builtin_amdgcn_mfma_f32_16x16x32_bf16(
                         aK1, bQ, (f32x4){0.f, 0.f, 0.f, 0.f}, 0, 0, 0);

            const short* vrow = Vt + nn * VSTR + kb + quad * 4;
            const short4v v0 = *reinterpret_cast<const short4v*>(vrow);
            const short4v v1 = *reinterpret_cast<const short4v*>(vrow + 16);

            const int keyb = kb + quad * 4;
            short8 aP, bV;
#pragma unroll
            for (int r = 0; r < 4; ++r) {
                const float e0 = (keyb + r <= qcol) ? exp2f(s0[r] * SC2) : 0.f;
                const float e1 = (doH1 && (keyb + 16 + r <= qcol))
                                     ? exp2f(s1[r] * SC2) : 0.f;
                aP[r]     = f2bf(e0);
                aP[4 + r] = f2bf(e1);
                bV[r]     = v0[r];
                bV[4 + r] = v1[r];
            }
            accO = __builtin_amdgcn_mfma_f32_16x16x32_bf16(aP, bV, accO, 0, 0, 0);
        }

#pragma unroll
        for (int r = 0; r < 4; ++r) {
            const float dn = __shfl(accO[r], (lane & 48) | 8);
            if (nn < 8) {
                const int q = qb + quad * 4 + r;
                out[((size_t)b * TT + q) * HH + nn] = accO[r] / dn;
            }
        }
    };

    // LDS-visibility barrier that does NOT drain vmcnt (prefetch rides through)
    auto barrier_lds = [&]() {
        asm volatile("s_waitcnt lgkmcnt(0)" ::: "memory");
        __builtin_amdgcn_s_barrier();
        __builtin_amdgcn_sched_barrier(0);
    };

    // ================= schedule =================
    issue(0);                              // chunk-0 x loads start immediately
    __builtin_amdgcn_sched_barrier(0);

    // Vt rows 8..15: row 8 = ones (denom column), rows 9..15 = 0
    {
        uint32_t* vtw = (uint32_t*)Vt;
        const int base = (8 * VSTR) / 2;
        for (int i = tid; i < (8 * VSTR) / 2; i += 256)
            vtw[base + i] = (i < VSTR / 2) ? 0x3F803F80u : 0u;
    }
    // W-fragment preload into Wl (sets distributed across waves).
    // Verified frag layout: B[k=quad*8+j][n=lane&15]; set = kt*2 + {QK,V}
    {
        const float* Wsel0 = (nn < 8) ? (Wq + nn) : (Wk + nn - 8);
        const float* Wsel1 = Wv + (nn & 7);         // safe ptr; masked by nn<8
        for (int set = wv; set < WSETS; set += 4) {
            const int kt = set >> 1, sv = set & 1;
            short8 frag;
#pragma unroll
            for (int j = 0; j < 8; ++j) {
                const int k = kt * 32 + quad * 8 + j;
                float v = 0.f;
                if (k < CC) {
                    if (sv == 0)        v = Wsel0[(size_t)k * HH];
                    else if (nn < 8)    v = Wsel1[(size_t)k * HH];
                }
                frag[j] = f2bf(v);
            }
            *reinterpret_cast<short8*>(Wl + (set * 16 + nn) * WLSTR + quad * 8) = frag;
        }
    }
    barrier_lds();                 // Wl + Vt init visible

    consume(0);                    // rows 0..63 -> LDS
    issue(1);                      // chunk-1 loads in flight across attn
    __builtin_amdgcn_sched_barrier(0);
    barrier_lds();                 // rows 0..63 visible

    attn_tile(wv);                 // tiles 0..3   (chunks 1,1,2,2)
    consume(1);                    // rows 64..127
    issue(2);
    __builtin_amdgcn_sched_barrier(0);
    barrier_lds();                 // rows 0..127 visible

    attn_tile(4 + (wv ^ 1));       // tiles 4..7   (chunks 3,3,4,4)
    consume(2);                    // rows 128..191
    issue(3);
    __builtin_amdgcn_sched_barrier(0);
    barrier_lds();                 // rows 0..191 visible

    attn_tile(8 + (wv ^ 2));       // tiles 8..11  (chunks 6,6,5,5)
    consume(3);                    // rows 192..255
    barrier_lds();                 // all rows visible

    attn_tile(12 + (wv ^ 3));      // tiles 12..15 (chunks 8,8,7,7)
}

extern "C" void kernel_launch(void* const* d_in, const int* in_sizes, int n_in,
                              void* d_out, int out_size, void* d_ws, size_t ws_size,
                              hipStream_t stream)
{
    const float* x  = (const float*)d_in[0];
    const float* Wq = (const float*)d_in[1];
    const float* Wk = (const float*)d_in[2];
    const float* Wv = (const float*)d_in[3];
    float* out      = (float*)d_out;
    const int B = in_sizes[0] / (TT * CC);   // = 1024
    fused_head<<<dim3(B), dim3(256), 0, stream>>>(x, Wq, Wk, Wv, out);
}